// Round 4
// baseline (2891.662 us; speedup 1.0000x reference)
//
#include <hip/hip_runtime.h>
#include <cstdint>
#include <cstddef>

#define B_  128
#define P_  196
#define F_  2048
#define H_  512
#define NF_ 512
#define E_  512
#define V_  10000
#define L_  20
#define T_  19
#define NPAD_ 10112            // 79*128 padded V
#define NCP_ (2560 + NPAD_)    // combo(2560) + preds cols = 12672

typedef short s8v __attribute__((ext_vector_type(8)));
typedef float f32x4 __attribute__((ext_vector_type(4)));

__device__ __forceinline__ float sigf(float x) { return 1.0f / (1.0f + expf(-x)); }
__device__ __forceinline__ ushort f2b(float f) {
    unsigned u = __builtin_bit_cast(unsigned, f);
    u += 0x7fff + ((u >> 16) & 1);          // RNE
    return (ushort)(u >> 16);
}
__device__ __forceinline__ float b2f(ushort h) {
    unsigned u = ((unsigned)h) << 16;
    return __builtin_bit_cast(float, u);
}

// ---------------- cast fp32 matrix -> bf16 (with optional zero row-padding) ---
__global__ __launch_bounds__(256)
void cast_mat(const float* __restrict__ s, ushort* __restrict__ d,
              long long total, int cols, int sld, int srows) {
    long long i4 = ((long long)blockIdx.x * 256 + threadIdx.x) * 4;
    if (i4 >= total) return;
    int n = (int)(i4 / cols);
    int k = (int)(i4 - (long long)n * cols);
    float4 v = make_float4(0.f, 0.f, 0.f, 0.f);
    if (n < srows) v = *(const float4*)(s + (size_t)n * sld + k);
    ushort4 o;
    o.x = f2b(v.x); o.y = f2b(v.y); o.z = f2b(v.z); o.w = f2b(v.w);
    *(ushort4*)(d + i4) = o;
}

// ------- cast with gate-interleave row permutation: row n' -> src row (n'&3)*H + (n'>>2)
__global__ __launch_bounds__(256)
void cast_perm(const float* __restrict__ s, ushort* __restrict__ d,
               int cols, int sld) {
    int idx = blockIdx.x * 256 + threadIdx.x;   // over 2048*cols/4
    int i4 = idx * 4;
    int n = i4 / cols;
    int k = i4 - n * cols;
    int r = (n & 3) * H_ + (n >> 2);
    float4 v = *(const float4*)(s + (size_t)r * sld + k);
    ushort4 o;
    o.x = f2b(v.x); o.y = f2b(v.y); o.z = f2b(v.z); o.w = f2b(v.w);
    *(ushort4*)(d + (size_t)n * cols + k) = o;
}

__global__ __launch_bounds__(256)
void build_bg(const float* __restrict__ bih, const float* __restrict__ bhh,
              float* __restrict__ bg) {
    int n = blockIdx.x * 256 + threadIdx.x;     // 2048
    int r = (n & 3) * H_ + (n >> 2);
    bg[n] = bih[r] + bhh[r];
}

__global__ __launch_bounds__(256)
void build_bcp(const float* __restrict__ bha, const float* __restrict__ bfb,
               const float* __restrict__ bfc, float* __restrict__ bcp) {
    int n = blockIdx.x * 256 + threadIdx.x;
    if (n >= NCP_) return;
    float v;
    if (n < 512) v = bha[n];
    else if (n < 2560) v = bfb[n - 512];
    else { int r = n - 2560; v = (r < V_) ? bfc[r] : 0.0f; }
    bcp[n] = v;
}

// ---------------- mean over P ----------------
template <int BF>
__global__ __launch_bounds__(256) void mean_kernel(const void* __restrict__ encv,
                                                   float* __restrict__ feat) {
    int b = blockIdx.x >> 3;
    int f = ((blockIdx.x & 7) << 8) + threadIdx.x;
    float s = 0.0f;
    if (BF) {
        const ushort* p = (const ushort*)encv + (size_t)b * P_ * F_ + f;
        for (int q = 0; q < P_; q++) s += b2f(p[(size_t)q * F_]);
    } else {
        const float* p = (const float*)encv + (size_t)b * P_ * F_ + f;
        for (int q = 0; q < P_; q++) s += p[(size_t)q * F_];
    }
    feat[b * F_ + f] = s * (1.0f / 196.0f);
}

// ---------------- embedding gather -> bf16 ----------------
__global__ __launch_bounds__(256) void gather_b(const float* __restrict__ emb,
                                                const int* __restrict__ gt,
                                                ushort* __restrict__ embx) {
    int idx = blockIdx.x * 256 + threadIdx.x;
    int i4 = idx * 4;
    int e = i4 & (E_ - 1);
    int bt = i4 >> 9;
    int b = bt / T_, t = bt - b * T_;
    int tok = gt[b * L_ + t];
    float4 v = *(const float4*)(emb + (size_t)tok * E_ + e);
    ushort4 o;
    o.x = f2b(v.x); o.y = f2b(v.y); o.z = f2b(v.z); o.w = f2b(v.w);
    *(ushort4*)(embx + i4) = o;
}

// ---------------- fp32 GEMM (fallback feat_att only) -------------
__global__ __launch_bounds__(256)
void gemm_biasb(const float* __restrict__ A, int lda,
                const float* __restrict__ W, int ldw,
                const float* __restrict__ bias,
                ushort* __restrict__ C, long long ldc,
                int M, int N, int K) {
    __shared__ float As[16][65];
    __shared__ float Ws[16][65];
    const int tid = threadIdx.x;
    const int m0 = blockIdx.y << 6;
    const int n0 = blockIdx.x << 6;
    const int row = tid >> 2;
    const int kq  = (tid & 3) << 2;
    const int ty = tid >> 4, tx = tid & 15;
    float acc[4][4] = {};
    for (int k0 = 0; k0 < K; k0 += 16) {
        float4 av = make_float4(0.f, 0.f, 0.f, 0.f);
        float4 wv = make_float4(0.f, 0.f, 0.f, 0.f);
        int m = m0 + row;
        if (m < M) av = *(const float4*)(A + (size_t)m * lda + k0 + kq);
        int n = n0 + row;
        if (n < N) wv = *(const float4*)(W + (size_t)n * ldw + k0 + kq);
        __syncthreads();
        As[kq + 0][row] = av.x; As[kq + 1][row] = av.y;
        As[kq + 2][row] = av.z; As[kq + 3][row] = av.w;
        Ws[kq + 0][row] = wv.x; Ws[kq + 1][row] = wv.y;
        Ws[kq + 2][row] = wv.z; Ws[kq + 3][row] = wv.w;
        __syncthreads();
#pragma unroll
        for (int k = 0; k < 16; k++) {
            float a[4], w[4];
#pragma unroll
            for (int i = 0; i < 4; i++) a[i] = As[k][(ty << 2) + i];
#pragma unroll
            for (int j = 0; j < 4; j++) w[j] = Ws[k][(tx << 2) + j];
#pragma unroll
            for (int i = 0; i < 4; i++)
#pragma unroll
                for (int j = 0; j < 4; j++)
                    acc[i][j] = fmaf(a[i], w[j], acc[i][j]);
        }
    }
#pragma unroll
    for (int i = 0; i < 4; i++) {
        int m = m0 + (ty << 2) + i;
        if (m >= M) continue;
#pragma unroll
        for (int j = 0; j < 4; j++) {
            int n = n0 + (tx << 2) + j;
            if (n >= N) continue;
            C[(size_t)m * ldc + n] = f2b(acc[i][j] + bias[n]);
        }
    }
}

// ---------------- bf16 MFMA GEMM ----------------
enum { MEPI_NONE = 0, MEPI_BIAS = 1, MEPI_BIASB = 2, MEPI_COMBOPRED = 3 };

__device__ __forceinline__ void stage_tile(const ushort* __restrict__ g, int ld,
                                           int row0, int k0, ushort* lds,
                                           int rows, int w, int l) {
    int nchunk = rows >> 4;                  // 1024 B (16 rows) per chunk
    for (int c = w; c < nchunk; c += 4) {
        int flat = c * 1024 + l * 16;
        int r = flat >> 6;
        int ce = (flat & 63) >> 1;
        const ushort* gp = g + (size_t)(row0 + r) * ld + (k0 + ce);
        __builtin_amdgcn_global_load_lds(
            (const __attribute__((address_space(1))) void*)gp,
            (__attribute__((address_space(3))) void*)(lds + c * 512),
            16, 0, 0);
    }
}

template <int BM, int EPI, int DUAL>
__global__ __launch_bounds__(256)
void mfma_gemm(const ushort* __restrict__ A1, int lda1,
               const ushort* __restrict__ W1, int ldw1, int K1,
               const ushort* __restrict__ A2, int lda2,
               const ushort* __restrict__ W2, int ldw2, int K2,
               const float* __restrict__ bias, void* __restrict__ Cout, long long ldc,
               void* __restrict__ Cout2,
               int M, int N,
               const int* __restrict__ clen, int tcur) {
    __shared__ ushort As[BM * 32];
    __shared__ ushort Bs[128 * 32];
    const int tid = threadIdx.x;
    const int w = tid >> 6, l = tid & 63;
    const int wr = w >> 1, wc = w & 1;
    constexpr int WM = BM / 2;
    constexpr int AF = WM / 16;
    const int m0 = blockIdx.y * BM;
    const int n0 = blockIdx.x * 128;
    const int lrow = l & 15, lk8 = (l >> 4) * 8;
    const int kz = blockIdx.z, nzz = gridDim.z;

    f32x4 acc[AF][4] = {};

    for (int pass = 0; pass < 1 + DUAL; pass++) {
        const ushort* A = pass ? A2 : A1;
        const ushort* W = pass ? W2 : W1;
        const int lda = pass ? lda2 : lda1;
        const int ldw = pass ? ldw2 : ldw1;
        const int K  = pass ? K2 : K1;
        const int chunk = K / nzz;
        const int kbeg = kz * chunk;
        const int kend = kbeg + chunk;
        for (int k0 = kbeg; k0 < kend; k0 += 32) {
            __syncthreads();
            stage_tile(A, lda, m0, k0, As, BM, w, l);
            stage_tile(W, ldw, n0, k0, Bs, 128, w, l);
            __syncthreads();
            s8v af[AF], bf[4];
#pragma unroll
            for (int i = 0; i < AF; i++)
                af[i] = *(const s8v*)(As + (wr * WM + i * 16 + lrow) * 32 + lk8);
#pragma unroll
            for (int j = 0; j < 4; j++)
                bf[j] = *(const s8v*)(Bs + (wc * 64 + j * 16 + lrow) * 32 + lk8);
#pragma unroll
            for (int i = 0; i < AF; i++)
#pragma unroll
                for (int j = 0; j < 4; j++)
                    acc[i][j] = __builtin_amdgcn_mfma_f32_16x16x32_bf16(
                        af[i], bf[j], acc[i][j], 0, 0, 0);
        }
    }

    float* Cz = (float*)Cout + (size_t)kz * (size_t)M * ldc;   // z-partials (MEPI_NONE)
#pragma unroll
    for (int i = 0; i < AF; i++) {
        int rb = m0 + wr * WM + i * 16 + (l >> 4) * 4;
#pragma unroll
        for (int j = 0; j < 4; j++) {
            int n = n0 + wc * 64 + j * 16 + (l & 15);
            if (n >= N) continue;
#pragma unroll
            for (int r = 0; r < 4; r++) {
                int m = rb + r;
                float v = acc[i][j][r];
                if (EPI == MEPI_NONE) {
                    Cz[(size_t)m * ldc + n] = v;
                } else if (EPI == MEPI_BIAS) {
                    ((float*)Cout)[(size_t)m * ldc + n] = v + bias[n];
                } else if (EPI == MEPI_BIASB) {
                    ((ushort*)Cout)[(size_t)m * ldc + n] = f2b(v + bias[n]);
                } else if (EPI == MEPI_COMBOPRED) {
                    if (n < 2560) {
                        ((float*)Cout)[(size_t)m * 2560 + n] = v + bias[n];
                    } else {
                        int col = n - 2560;
                        if (col < V_) {
                            float mk = (tcur < clen[m] - 1) ? 1.0f : 0.0f;
                            ((float*)Cout2)[(size_t)m * ((long long)T_ * V_) + col] =
                                (v + bias[n]) * mk;
                        }
                    }
                }
            }
        }
    }
}

// ---------------- h0/c0 finalize ----------------
__global__ __launch_bounds__(256)
void h0c0_final(const float* __restrict__ part,   // 4 x B x 1024
                const float* __restrict__ b0,
                const float* __restrict__ g0,
                const float* __restrict__ bt0,
                float* __restrict__ cbuf, ushort* __restrict__ hb) {
    int idx = blockIdx.x * 256 + threadIdx.x;   // B*512
    int b = idx >> 9, j = idx & 511;
    const float rbn = 1.0f / sqrtf(1.0f + 1e-5f);
    float sh = b0[j], sc = b0[j + 512];
    for (int z = 0; z < 4; z++) {
        sh += part[((size_t)z * B_ + b) * 1024 + j];
        sc += part[((size_t)z * B_ + b) * 1024 + j + 512];
    }
    float hv = g0[j] * (sigf(sh) * rbn) + bt0[j];
    float cv = g0[j + 512] * (sigf(sc) * rbn) + bt0[j + 512];
    cbuf[idx] = cv;
    hb[idx] = f2b(hv);
}

// ---- fused attention score + softmax + context + input-gate ----
// 2 blocks per batch row; each block computes all 196 scores (redundant, cheap),
// softmaxes in LDS, then accumulates its half of context and writes gated bf16.
template <int BF>
__global__ __launch_bounds__(256)
void attn_ctx(const void* __restrict__ encv, const ushort* __restrict__ fa,
              const float* __restrict__ combo, const float* __restrict__ Wv,
              float* __restrict__ alphas_out, const int* __restrict__ clen,
              ushort* __restrict__ gctxb, int t) {
    int b = blockIdx.x >> 1;
    int half = blockIdx.x & 1;
    int tid = threadIdx.x;
    int w = tid >> 6, l = tid & 63;
    __shared__ float eS[256];
    __shared__ float red[256];
    const float* hap = combo + (size_t)b * 2560;
    float ha8[8], wv8[8];
#pragma unroll
    for (int i = 0; i < 8; i++) { ha8[i] = hap[l * 8 + i]; wv8[i] = Wv[l * 8 + i]; }
    eS[tid] = -1e30f;
    __syncthreads();
    const ushort* fab = fa + (size_t)b * P_ * NF_;
    for (int p = w; p < P_; p += 4) {
        const ushort* fp = fab + (size_t)p * NF_ + l * 8;
        ushort4 u0 = *(const ushort4*)fp;
        ushort4 u1 = *(const ushort4*)(fp + 4);
        float s = 0.0f, v;
        v = b2f(u0.x) + ha8[0]; v = v > 0.f ? v : 0.f; s = fmaf(v, wv8[0], s);
        v = b2f(u0.y) + ha8[1]; v = v > 0.f ? v : 0.f; s = fmaf(v, wv8[1], s);
        v = b2f(u0.z) + ha8[2]; v = v > 0.f ? v : 0.f; s = fmaf(v, wv8[2], s);
        v = b2f(u0.w) + ha8[3]; v = v > 0.f ? v : 0.f; s = fmaf(v, wv8[3], s);
        v = b2f(u1.x) + ha8[4]; v = v > 0.f ? v : 0.f; s = fmaf(v, wv8[4], s);
        v = b2f(u1.y) + ha8[5]; v = v > 0.f ? v : 0.f; s = fmaf(v, wv8[5], s);
        v = b2f(u1.z) + ha8[6]; v = v > 0.f ? v : 0.f; s = fmaf(v, wv8[6], s);
        v = b2f(u1.w) + ha8[7]; v = v > 0.f ? v : 0.f; s = fmaf(v, wv8[7], s);
#pragma unroll
        for (int off = 32; off > 0; off >>= 1) s += __shfl_down(s, off, 64);
        if (l == 0) eS[p] = s;
    }
    __syncthreads();
    float ev = eS[tid];
    red[tid] = ev;
    __syncthreads();
    for (int s = 128; s > 0; s >>= 1) {
        if (tid < s) red[tid] = fmaxf(red[tid], red[tid + s]);
        __syncthreads();
    }
    float mx = red[0];
    __syncthreads();
    float ex = expf(ev - mx);
    red[tid] = ex;
    __syncthreads();
    for (int s = 128; s > 0; s >>= 1) {
        if (tid < s) red[tid] += red[tid + s];
        __syncthreads();
    }
    float inv = 1.0f / red[0];
    float a = ex * inv;
    __syncthreads();
    eS[tid] = a;                     // alpha now in LDS
    if (half == 0 && tid < P_) {
        float m = (t < clen[b] - 1) ? 1.0f : 0.0f;
        alphas_out[((size_t)b * T_ + t) * P_ + tid] = a * m;
    }
    __syncthreads();

    // context over this block's half of F
    int f0 = (half << 10) + tid * 4;
    float s0 = 0.f, s1 = 0.f, s2 = 0.f, s3 = 0.f;
    if (BF) {
        const ushort* ep = (const ushort*)encv + (size_t)b * P_ * F_ + f0;
#pragma unroll 2
        for (int p = 0; p < P_; p++) {
            ushort4 u = *(const ushort4*)(ep + (size_t)p * F_);
            float al = eS[p];
            s0 = fmaf(al, b2f(u.x), s0);
            s1 = fmaf(al, b2f(u.y), s1);
            s2 = fmaf(al, b2f(u.z), s2);
            s3 = fmaf(al, b2f(u.w), s3);
        }
    } else {
        const float* ep = (const float*)encv + (size_t)b * P_ * F_ + f0;
#pragma unroll 2
        for (int p = 0; p < P_; p++) {
            float4 u = *(const float4*)(ep + (size_t)p * F_);
            float al = eS[p];
            s0 = fmaf(al, u.x, s0);
            s1 = fmaf(al, u.y, s1);
            s2 = fmaf(al, u.z, s2);
            s3 = fmaf(al, u.w, s3);
        }
    }
    float4 g4 = *(const float4*)(combo + (size_t)b * 2560 + 512 + f0);
    ushort4 o;
    o.x = f2b(sigf(g4.x) * s0);
    o.y = f2b(sigf(g4.y) * s1);
    o.z = f2b(sigf(g4.z) * s2);
    o.w = f2b(sigf(g4.w) * s3);
    *(ushort4*)(gctxb + (size_t)b * F_ + f0) = o;
}

// ---- gates GEMM (gate-interleaved cols) + full LSTM cell epilogue ----
// grid (16, 4): block = 32 rows x 128 cols; cols are 32 complete hidden units.
__global__ __launch_bounds__(256)
void gates_lstm(const ushort* __restrict__ gctxb, const ushort* __restrict__ WihFbP,
                const ushort* __restrict__ hin, const ushort* __restrict__ WhhbP,
                const float* __restrict__ embprojP, const float* __restrict__ bg,
                float* __restrict__ cbuf, ushort* __restrict__ hout, int t) {
    __shared__ ushort As[32 * 32];
    __shared__ ushort Bs[128 * 32];
    __shared__ float Cs[32 * 128];
    const int tid = threadIdx.x;
    const int w = tid >> 6, l = tid & 63;
    const int wr = w >> 1, wc = w & 1;
    const int m0 = blockIdx.y * 32;
    const int n0 = blockIdx.x * 128;
    const int lrow = l & 15, lk8 = (l >> 4) * 8;
    f32x4 acc[4] = {};

    for (int pass = 0; pass < 2; pass++) {
        const ushort* A = pass ? hin : gctxb;
        const ushort* W = pass ? WhhbP : WihFbP;
        const int lda = pass ? H_ : F_;
        const int K  = pass ? H_ : F_;
        for (int k0 = 0; k0 < K; k0 += 32) {
            __syncthreads();
            stage_tile(A, lda, m0, k0, As, 32, w, l);
            stage_tile(W, lda, n0, k0, Bs, 128, w, l);
            __syncthreads();
            s8v af = *(const s8v*)(As + (wr * 16 + lrow) * 32 + lk8);
            s8v bf[4];
#pragma unroll
            for (int j = 0; j < 4; j++)
                bf[j] = *(const s8v*)(Bs + (wc * 64 + j * 16 + lrow) * 32 + lk8);
#pragma unroll
            for (int j = 0; j < 4; j++)
                acc[j] = __builtin_amdgcn_mfma_f32_16x16x32_bf16(af, bf[j], acc[j], 0, 0, 0);
        }
    }

    // dump acc to LDS: local (m, n) = (rb - m0 + r, wc*64 + j*16 + (l&15))
    int rbl = wr * 16 + (l >> 4) * 4;
#pragma unroll
    for (int j = 0; j < 4; j++) {
        int nl = wc * 64 + j * 16 + (l & 15);
#pragma unroll
        for (int r = 0; r < 4; r++)
            Cs[(rbl + r) * 128 + nl] = acc[j][r];
    }
    __syncthreads();

    // LSTM: 32 m x 32 units per block; 1024 pairs / 256 threads
#pragma unroll
    for (int it = 0; it < 4; it++) {
        int idx = it * 256 + tid;
        int ml = idx >> 5, jl = idx & 31;
        int m = m0 + ml;
        int j = (n0 >> 2) + jl;
        const float* ep = embprojP + ((size_t)m * T_ + t) * 2048 + n0 + jl * 4;
        const float* bgp = bg + n0 + jl * 4;
        float g0 = Cs[ml * 128 + jl * 4 + 0] + ep[0] + bgp[0];
        float g1 = Cs[ml * 128 + jl * 4 + 1] + ep[1] + bgp[1];
        float g2 = Cs[ml * 128 + jl * 4 + 2] + ep[2] + bgp[2];
        float g3 = Cs[ml * 128 + jl * 4 + 3] + ep[3] + bgp[3];
        float cn = sigf(g1) * cbuf[m * H_ + j] + sigf(g0) * tanhf(g2);
        float hn = sigf(g3) * tanhf(cn);
        cbuf[m * H_ + j] = cn;
        hout[m * H_ + j] = f2b(hn);
    }
}

extern "C" void kernel_launch(void* const* d_in, const int* in_sizes, int n_in,
                              void* d_out, int out_size, void* d_ws, size_t ws_size,
                              hipStream_t stream) {
    const float* enc = (const float*)d_in[0];
    const float* emb = (const float*)d_in[1];
    const float* Wfa = (const float*)d_in[2];
    const float* bfa = (const float*)d_in[3];
    const float* Wha = (const float*)d_in[4];
    const float* bha = (const float*)d_in[5];
    const float* Wv  = (const float*)d_in[6];
    const float* Wh0 = (const float*)d_in[8];
    const float* bh0 = (const float*)d_in[9];
    const float* Wc0 = (const float*)d_in[10];
    const float* bc0 = (const float*)d_in[11];
    const float* gh  = (const float*)d_in[12];
    const float* bth = (const float*)d_in[13];
    const float* gc  = (const float*)d_in[14];
    const float* btc = (const float*)d_in[15];
    const float* Wfb = (const float*)d_in[16];
    const float* bfb = (const float*)d_in[17];
    const float* Wih = (const float*)d_in[18];
    const float* Whh = (const float*)d_in[19];
    const float* bih = (const float*)d_in[20];
    const float* bhh = (const float*)d_in[21];
    const float* Wfc = (const float*)d_in[22];
    const float* bfc = (const float*)d_in[23];
    const int* gt   = (const int*)d_in[24];
    const int* clen = (const int*)d_in[25];

    float* out_pred  = (float*)d_out;                       // (B,T,V)
    float* out_alpha = out_pred + (size_t)B_ * T_ * V_;     // (B,T,P)

    char* wp = (char*)d_ws;
    auto alloc = [&](size_t bytes) {
        char* p = wp;
        wp += (bytes + 255) & ~(size_t)255;
        return p;
    };
    float*  feat     = (float*)alloc((size_t)B_ * F_ * 4);
    float*  cbuf     = (float*)alloc((size_t)B_ * H_ * 4);
    float*  combo    = (float*)alloc((size_t)B_ * 2560 * 4);
    float*  embprojP = (float*)alloc((size_t)B_ * T_ * 2048 * 4);
    float*  hcpart   = (float*)alloc((size_t)4 * B_ * 1024 * 4);
    float*  bcp      = (float*)alloc((size_t)NCP_ * 4);
    float*  bg       = (float*)alloc(2048 * 4);
    float*  b0comb   = (float*)alloc(1024 * 4);
    float*  g0comb   = (float*)alloc(1024 * 4);
    float*  bt0comb  = (float*)alloc(1024 * 4);
    ushort* hb0      = (ushort*)alloc((size_t)B_ * H_ * 2);
    ushort* hb1      = (ushort*)alloc((size_t)B_ * H_ * 2);
    ushort* gctxb    = (ushort*)alloc((size_t)B_ * F_ * 2);
    ushort* embxb    = (ushort*)alloc((size_t)B_ * T_ * E_ * 2);
    ushort* fattb    = (ushort*)alloc((size_t)B_ * P_ * NF_ * 2);
    ushort* featb    = (ushort*)alloc((size_t)B_ * F_ * 2);
    ushort* Wfab     = (ushort*)alloc((size_t)NF_ * F_ * 2);
    ushort* WihEbP   = (ushort*)alloc((size_t)2048 * E_ * 2);
    ushort* WihFbP   = (ushort*)alloc((size_t)2048 * F_ * 2);
    ushort* WhhbP    = (ushort*)alloc((size_t)2048 * H_ * 2);
    ushort* Wcp      = (ushort*)alloc((size_t)NCP_ * H_ * 2);
    ushort* W0comb   = (ushort*)alloc((size_t)1024 * F_ * 2);
    ushort* encb     = (ushort*)alloc((size_t)B_ * P_ * F_ * 2);
    const bool big = ((size_t)(wp - (char*)d_ws) <= ws_size);

    auto castM = [&](const float* s, ushort* d, long long rows, int cols, int sld, int srows) {
        long long total = rows * (long long)cols;
        cast_mat<<<(int)((total + 1023) / 1024), 256, 0, stream>>>(s, d, total, cols, sld, srows);
    };

    // ---- one-time casts / permutes / bias builds ----
    if (big) castM(enc, encb, (long long)B_ * P_, F_, F_, B_ * P_);
    castM(Wfa, Wfab, NF_, F_, F_, NF_);
    cast_perm<<<(2048 * E_) / 1024, 256, 0, stream>>>(Wih, WihEbP, E_, E_ + F_);
    cast_perm<<<(2048 * F_) / 1024, 256, 0, stream>>>(Wih + E_, WihFbP, F_, E_ + F_);
    cast_perm<<<(2048 * H_) / 1024, 256, 0, stream>>>(Whh, WhhbP, H_, H_);
    castM(Wha, Wcp, NF_, H_, H_, NF_);
    castM(Wfb, Wcp + (size_t)512 * H_, F_, H_, H_, F_);
    castM(Wfc, Wcp + (size_t)2560 * H_, NPAD_, H_, H_, V_);
    castM(Wh0, W0comb, H_, F_, F_, H_);
    castM(Wc0, W0comb + (size_t)H_ * F_, H_, F_, F_, H_);
    build_bg<<<2048 / 256, 256, 0, stream>>>(bih, bhh, bg);
    build_bcp<<<(NCP_ + 255) / 256, 256, 0, stream>>>(bha, bfb, bfc, bcp);
    hipMemcpyAsync(b0comb, bh0, H_ * 4, hipMemcpyDeviceToDevice, stream);
    hipMemcpyAsync(b0comb + H_, bc0, H_ * 4, hipMemcpyDeviceToDevice, stream);
    hipMemcpyAsync(g0comb, gh, H_ * 4, hipMemcpyDeviceToDevice, stream);
    hipMemcpyAsync(g0comb + H_, gc, H_ * 4, hipMemcpyDeviceToDevice, stream);
    hipMemcpyAsync(bt0comb, bth, H_ * 4, hipMemcpyDeviceToDevice, stream);
    hipMemcpyAsync(bt0comb + H_, btc, H_ * 4, hipMemcpyDeviceToDevice, stream);

    // ---- init state ----
    if (big) mean_kernel<1><<<B_ * 8, 256, 0, stream>>>(encb, feat);
    else     mean_kernel<0><<<B_ * 8, 256, 0, stream>>>(enc, feat);
    castM(feat, featb, B_, F_, F_, B_);
    mfma_gemm<32, MEPI_NONE, 0><<<dim3(1024 / 128, B_ / 32, 4), 256, 0, stream>>>(
        featb, F_, W0comb, F_, F_, nullptr, 0, nullptr, 0, 0,
        nullptr, hcpart, 1024, nullptr, B_, 1024, nullptr, 0);
    h0c0_final<<<(B_ * H_) / 256, 256, 0, stream>>>(hcpart, b0comb, g0comb, bt0comb, cbuf, hb0);
    gather_b<<<(B_ * T_ * E_) / 1024, 256, 0, stream>>>(emb, gt, embxb);

    // ---- feat_att (bf16 out) ----
    if (big) {
        mfma_gemm<128, MEPI_BIASB, 0><<<dim3(NF_ / 128, (B_ * P_) / 128, 1), 256, 0, stream>>>(
            encb, F_, Wfab, F_, F_, nullptr, 0, nullptr, 0, 0,
            bfa, fattb, NF_, nullptr, B_ * P_, NF_, nullptr, 0);
    } else {
        gemm_biasb<<<dim3(NF_ / 64, (B_ * P_) / 64), 256, 0, stream>>>(
            enc, F_, Wfa, F_, bfa, fattb, NF_, B_ * P_, NF_, F_);
    }
    // ---- embprojP = embx @ WihEbP^T (fp32, gate-interleaved cols) ----
    mfma_gemm<128, MEPI_NONE, 0><<<dim3(2048 / 128, (B_ * T_) / 128, 1), 256, 0, stream>>>(
        embxb, E_, WihEbP, E_, E_, nullptr, 0, nullptr, 0, 0,
        nullptr, embprojP, 2048, nullptr, B_ * T_, 2048, nullptr, 0);

    // ---- combo(0) from h0 ----
    mfma_gemm<32, MEPI_BIAS, 0><<<dim3(2560 / 128, B_ / 32, 1), 256, 0, stream>>>(
        hb0, H_, Wcp, H_, H_, nullptr, 0, nullptr, 0, 0,
        bcp, combo, 2560, nullptr, B_, 2560, nullptr, 0);

    // ---- recurrent scan: 3 launches per step ----
    for (int t = 0; t < T_; t++) {
        ushort* hin  = (t & 1) ? hb1 : hb0;
        ushort* hout = (t & 1) ? hb0 : hb1;
        if (big) attn_ctx<1><<<B_ * 2, 256, 0, stream>>>(encb, fattb, combo, Wv,
                                                         out_alpha, clen, gctxb, t);
        else     attn_ctx<0><<<B_ * 2, 256, 0, stream>>>(enc, fattb, combo, Wv,
                                                         out_alpha, clen, gctxb, t);
        gates_lstm<<<dim3(2048 / 128, B_ / 32), 256, 0, stream>>>(
            gctxb, WihFbP, hin, WhhbP, embprojP, bg, cbuf, hout, t);
        // combo(t+1) + preds(t) from h_new
        mfma_gemm<32, MEPI_COMBOPRED, 0><<<dim3(NCP_ / 128, B_ / 32, 1), 256, 0, stream>>>(
            hout, H_, Wcp, H_, H_, nullptr, 0, nullptr, 0, 0,
            bcp, combo, 2560, out_pred + (size_t)t * V_, B_, NCP_, clen, t);
    }
}

// Round 5
// 2070.225 us; speedup vs baseline: 1.3968x; 1.3968x over previous
//
#include <hip/hip_runtime.h>
#include <cstdint>
#include <cstddef>

#define B_  128
#define P_  196
#define F_  2048
#define H_  512
#define NF_ 512
#define E_  512
#define V_  10000
#define L_  20
#define T_  19
#define NPAD_ 10112            // 79*128 padded V
#define NCP_ (2560 + NPAD_)    // combo(2560) + preds cols = 12672

typedef short s8v __attribute__((ext_vector_type(8)));
typedef float f32x4 __attribute__((ext_vector_type(4)));
typedef unsigned short u16x8 __attribute__((ext_vector_type(8)));

__device__ __forceinline__ float sigf(float x) { return 1.0f / (1.0f + expf(-x)); }
__device__ __forceinline__ ushort f2b(float f) {
    unsigned u = __builtin_bit_cast(unsigned, f);
    u += 0x7fff + ((u >> 16) & 1);          // RNE
    return (ushort)(u >> 16);
}
__device__ __forceinline__ float b2f(ushort h) {
    unsigned u = ((unsigned)h) << 16;
    return __builtin_bit_cast(float, u);
}

// ---------------- cast fp32 matrix -> bf16 (with optional zero row-padding) ---
__global__ __launch_bounds__(256)
void cast_mat(const float* __restrict__ s, ushort* __restrict__ d,
              long long total, int cols, int sld, int srows) {
    long long i4 = ((long long)blockIdx.x * 256 + threadIdx.x) * 4;
    if (i4 >= total) return;
    int n = (int)(i4 / cols);
    int k = (int)(i4 - (long long)n * cols);
    float4 v = make_float4(0.f, 0.f, 0.f, 0.f);
    if (n < srows) v = *(const float4*)(s + (size_t)n * sld + k);
    ushort4 o;
    o.x = f2b(v.x); o.y = f2b(v.y); o.z = f2b(v.z); o.w = f2b(v.w);
    *(ushort4*)(d + i4) = o;
}

// ------- cast with gate-interleave row permutation: row n' -> src row (n'&3)*H + (n'>>2)
__global__ __launch_bounds__(256)
void cast_perm(const float* __restrict__ s, ushort* __restrict__ d,
               int cols, int sld) {
    int idx = blockIdx.x * 256 + threadIdx.x;   // over 2048*cols/4
    int i4 = idx * 4;
    int n = i4 / cols;
    int k = i4 - n * cols;
    int r = (n & 3) * H_ + (n >> 2);
    float4 v = *(const float4*)(s + (size_t)r * sld + k);
    ushort4 o;
    o.x = f2b(v.x); o.y = f2b(v.y); o.z = f2b(v.z); o.w = f2b(v.w);
    *(ushort4*)(d + (size_t)n * cols + k) = o;
}

__global__ __launch_bounds__(256)
void build_bg(const float* __restrict__ bih, const float* __restrict__ bhh,
              float* __restrict__ bg) {
    int n = blockIdx.x * 256 + threadIdx.x;     // 2048
    int r = (n & 3) * H_ + (n >> 2);
    bg[n] = bih[r] + bhh[r];
}

__global__ __launch_bounds__(256)
void build_bcp(const float* __restrict__ bha, const float* __restrict__ bfb,
               const float* __restrict__ bfc, float* __restrict__ bcp) {
    int n = blockIdx.x * 256 + threadIdx.x;
    if (n >= NCP_) return;
    float v;
    if (n < 512) v = bha[n];
    else if (n < 2560) v = bfb[n - 512];
    else { int r = n - 2560; v = (r < V_) ? bfc[r] : 0.0f; }
    bcp[n] = v;
}

// ------- fused: mean over P + cast enc -> bf16 (one fp32 pass) -------
__global__ __launch_bounds__(256)
void mean_cast_kernel(const float* __restrict__ enc, ushort* __restrict__ encb,
                      float* __restrict__ feat) {
    int b = blockIdx.x >> 3;
    int f = ((blockIdx.x & 7) << 8) + threadIdx.x;
    const float* p = enc + (size_t)b * P_ * F_ + f;
    ushort* pb = encb + (size_t)b * P_ * F_ + f;
    float s = 0.0f;
    for (int q = 0; q < P_; q++) {
        float v = p[(size_t)q * F_];
        pb[(size_t)q * F_] = f2b(v);
        s += v;
    }
    feat[b * F_ + f] = s * (1.0f / 196.0f);
}

// ---------------- mean only (fallback) ----------------
__global__ __launch_bounds__(256) void mean_kernel(const float* __restrict__ enc,
                                                   float* __restrict__ feat) {
    int b = blockIdx.x >> 3;
    int f = ((blockIdx.x & 7) << 8) + threadIdx.x;
    const float* p = enc + (size_t)b * P_ * F_ + f;
    float s = 0.0f;
    for (int q = 0; q < P_; q++) s += p[(size_t)q * F_];
    feat[b * F_ + f] = s * (1.0f / 196.0f);
}

// ---------------- embedding gather -> bf16 ----------------
__global__ __launch_bounds__(256) void gather_b(const float* __restrict__ emb,
                                                const int* __restrict__ gt,
                                                ushort* __restrict__ embx) {
    int idx = blockIdx.x * 256 + threadIdx.x;
    int i4 = idx * 4;
    int e = i4 & (E_ - 1);
    int bt = i4 >> 9;
    int b = bt / T_, t = bt - b * T_;
    int tok = gt[b * L_ + t];
    float4 v = *(const float4*)(emb + (size_t)tok * E_ + e);
    ushort4 o;
    o.x = f2b(v.x); o.y = f2b(v.y); o.z = f2b(v.z); o.w = f2b(v.w);
    *(ushort4*)(embx + i4) = o;
}

// ---------------- fp32 GEMM (fallback feat_att only) -------------
__global__ __launch_bounds__(256)
void gemm_biasb(const float* __restrict__ A, int lda,
                const float* __restrict__ W, int ldw,
                const float* __restrict__ bias,
                ushort* __restrict__ C, long long ldc,
                int M, int N, int K) {
    __shared__ float As[16][65];
    __shared__ float Ws[16][65];
    const int tid = threadIdx.x;
    const int m0 = blockIdx.y << 6;
    const int n0 = blockIdx.x << 6;
    const int row = tid >> 2;
    const int kq  = (tid & 3) << 2;
    const int ty = tid >> 4, tx = tid & 15;
    float acc[4][4] = {};
    for (int k0 = 0; k0 < K; k0 += 16) {
        float4 av = make_float4(0.f, 0.f, 0.f, 0.f);
        float4 wv = make_float4(0.f, 0.f, 0.f, 0.f);
        int m = m0 + row;
        if (m < M) av = *(const float4*)(A + (size_t)m * lda + k0 + kq);
        int n = n0 + row;
        if (n < N) wv = *(const float4*)(W + (size_t)n * ldw + k0 + kq);
        __syncthreads();
        As[kq + 0][row] = av.x; As[kq + 1][row] = av.y;
        As[kq + 2][row] = av.z; As[kq + 3][row] = av.w;
        Ws[kq + 0][row] = wv.x; Ws[kq + 1][row] = wv.y;
        Ws[kq + 2][row] = wv.z; Ws[kq + 3][row] = wv.w;
        __syncthreads();
#pragma unroll
        for (int k = 0; k < 16; k++) {
            float a[4], w[4];
#pragma unroll
            for (int i = 0; i < 4; i++) a[i] = As[k][(ty << 2) + i];
#pragma unroll
            for (int j = 0; j < 4; j++) w[j] = Ws[k][(tx << 2) + j];
#pragma unroll
            for (int i = 0; i < 4; i++)
#pragma unroll
                for (int j = 0; j < 4; j++)
                    acc[i][j] = fmaf(a[i], w[j], acc[i][j]);
        }
    }
#pragma unroll
    for (int i = 0; i < 4; i++) {
        int m = m0 + (ty << 2) + i;
        if (m >= M) continue;
#pragma unroll
        for (int j = 0; j < 4; j++) {
            int n = n0 + (tx << 2) + j;
            if (n >= N) continue;
            C[(size_t)m * ldc + n] = f2b(acc[i][j] + bias[n]);
        }
    }
}

// ---------------- bf16 MFMA GEMM ----------------
enum { MEPI_NONE = 0, MEPI_BIAS = 1, MEPI_BIASB = 2, MEPI_COMBOPRED = 3 };

__device__ __forceinline__ void stage_tile(const ushort* __restrict__ g, int ld,
                                           int row0, int k0, ushort* lds,
                                           int rows, int w, int l) {
    int nchunk = rows >> 4;                  // 1024 B (16 rows) per chunk
    for (int c = w; c < nchunk; c += 4) {
        int flat = c * 1024 + l * 16;
        int r = flat >> 6;
        int ce = (flat & 63) >> 1;
        const ushort* gp = g + (size_t)(row0 + r) * ld + (k0 + ce);
        __builtin_amdgcn_global_load_lds(
            (const __attribute__((address_space(1))) void*)gp,
            (__attribute__((address_space(3))) void*)(lds + c * 512),
            16, 0, 0);
    }
}

template <int BM, int EPI, int DUAL>
__global__ __launch_bounds__(256)
void mfma_gemm(const ushort* __restrict__ A1, int lda1,
               const ushort* __restrict__ W1, int ldw1, int K1,
               const ushort* __restrict__ A2, int lda2,
               const ushort* __restrict__ W2, int ldw2, int K2,
               const float* __restrict__ bias, void* __restrict__ Cout, long long ldc,
               void* __restrict__ Cout2,
               int M, int N,
               const int* __restrict__ clen, int tcur) {
    __shared__ ushort As[BM * 32];
    __shared__ ushort Bs[128 * 32];
    const int tid = threadIdx.x;
    const int w = tid >> 6, l = tid & 63;
    const int wr = w >> 1, wc = w & 1;
    constexpr int WM = BM / 2;
    constexpr int AF = WM / 16;
    const int m0 = blockIdx.y * BM;
    const int n0 = blockIdx.x * 128;
    const int lrow = l & 15, lk8 = (l >> 4) * 8;
    const int kz = blockIdx.z, nzz = gridDim.z;

    f32x4 acc[AF][4] = {};

    for (int pass = 0; pass < 1 + DUAL; pass++) {
        const ushort* A = pass ? A2 : A1;
        const ushort* W = pass ? W2 : W1;
        const int lda = pass ? lda2 : lda1;
        const int ldw = pass ? ldw2 : ldw1;
        const int K  = pass ? K2 : K1;
        const int chunk = K / nzz;
        const int kbeg = kz * chunk;
        const int kend = kbeg + chunk;
        for (int k0 = kbeg; k0 < kend; k0 += 32) {
            __syncthreads();
            stage_tile(A, lda, m0, k0, As, BM, w, l);
            stage_tile(W, ldw, n0, k0, Bs, 128, w, l);
            __syncthreads();
            s8v af[AF], bf[4];
#pragma unroll
            for (int i = 0; i < AF; i++)
                af[i] = *(const s8v*)(As + (wr * WM + i * 16 + lrow) * 32 + lk8);
#pragma unroll
            for (int j = 0; j < 4; j++)
                bf[j] = *(const s8v*)(Bs + (wc * 64 + j * 16 + lrow) * 32 + lk8);
#pragma unroll
            for (int i = 0; i < AF; i++)
#pragma unroll
                for (int j = 0; j < 4; j++)
                    acc[i][j] = __builtin_amdgcn_mfma_f32_16x16x32_bf16(
                        af[i], bf[j], acc[i][j], 0, 0, 0);
        }
    }

    float* Cz = (float*)Cout + (size_t)kz * (size_t)M * ldc;   // z-partials (MEPI_NONE)
#pragma unroll
    for (int i = 0; i < AF; i++) {
        int rb = m0 + wr * WM + i * 16 + (l >> 4) * 4;
#pragma unroll
        for (int j = 0; j < 4; j++) {
            int n = n0 + wc * 64 + j * 16 + (l & 15);
            if (n >= N) continue;
#pragma unroll
            for (int r = 0; r < 4; r++) {
                int m = rb + r;
                float v = acc[i][j][r];
                if (EPI == MEPI_NONE) {
                    Cz[(size_t)m * ldc + n] = v;
                } else if (EPI == MEPI_BIAS) {
                    ((float*)Cout)[(size_t)m * ldc + n] = v + bias[n];
                } else if (EPI == MEPI_BIASB) {
                    ((ushort*)Cout)[(size_t)m * ldc + n] = f2b(v + bias[n]);
                } else if (EPI == MEPI_COMBOPRED) {
                    if (n < 2560) {
                        ((float*)Cout)[(size_t)m * 2560 + n] = v + bias[n];
                    } else {
                        int col = n - 2560;
                        if (col < V_) {
                            float mk = (tcur < clen[m] - 1) ? 1.0f : 0.0f;
                            ((float*)Cout2)[(size_t)m * ((long long)T_ * V_) + col] =
                                (v + bias[n]) * mk;
                        }
                    }
                }
            }
        }
    }
}

// ---------------- h0/c0 finalize ----------------
__global__ __launch_bounds__(256)
void h0c0_final(const float* __restrict__ part,   // 4 x B x 1024
                const float* __restrict__ b0,
                const float* __restrict__ g0,
                const float* __restrict__ bt0,
                float* __restrict__ cbuf, ushort* __restrict__ hb) {
    int idx = blockIdx.x * 256 + threadIdx.x;   // B*512
    int b = idx >> 9, j = idx & 511;
    const float rbn = 1.0f / sqrtf(1.0f + 1e-5f);
    float sh = b0[j], sc = b0[j + 512];
    for (int z = 0; z < 4; z++) {
        sh += part[((size_t)z * B_ + b) * 1024 + j];
        sc += part[((size_t)z * B_ + b) * 1024 + j + 512];
    }
    float hv = g0[j] * (sigf(sh) * rbn) + bt0[j];
    float cv = g0[j + 512] * (sigf(sc) * rbn) + bt0[j + 512];
    cbuf[idx] = cv;
    hb[idx] = f2b(hv);
}

// ---- fused attention score + softmax + context + input-gate ----
// 2 blocks per batch row. Score phase: all 256 threads over all 196 p
// (redundant per half, cheap). Context phase: 128 col-threads x 8 cols
// (ushort8 loads) x 2 p-ranges, LDS-combined.
template <int BF>
__global__ __launch_bounds__(256)
void attn_ctx(const void* __restrict__ encv, const ushort* __restrict__ fa,
              const float* __restrict__ combo, const float* __restrict__ Wv,
              float* __restrict__ alphas_out, const int* __restrict__ clen,
              ushort* __restrict__ gctxb, int t) {
    int b = blockIdx.x >> 1;
    int half = blockIdx.x & 1;
    int tid = threadIdx.x;
    int w = tid >> 6, l = tid & 63;
    __shared__ float eS[256];
    __shared__ float red[256];
    __shared__ float pc[128 * 8];
    const float* hap = combo + (size_t)b * 2560;
    float ha8[8], wv8[8];
#pragma unroll
    for (int i = 0; i < 8; i++) { ha8[i] = hap[l * 8 + i]; wv8[i] = Wv[l * 8 + i]; }
    eS[tid] = -1e30f;
    __syncthreads();
    const ushort* fab = fa + (size_t)b * P_ * NF_;
    for (int p = w; p < P_; p += 4) {
        const ushort* fp = fab + (size_t)p * NF_ + l * 8;
        ushort4 u0 = *(const ushort4*)fp;
        ushort4 u1 = *(const ushort4*)(fp + 4);
        float s = 0.0f, v;
        v = b2f(u0.x) + ha8[0]; v = v > 0.f ? v : 0.f; s = fmaf(v, wv8[0], s);
        v = b2f(u0.y) + ha8[1]; v = v > 0.f ? v : 0.f; s = fmaf(v, wv8[1], s);
        v = b2f(u0.z) + ha8[2]; v = v > 0.f ? v : 0.f; s = fmaf(v, wv8[2], s);
        v = b2f(u0.w) + ha8[3]; v = v > 0.f ? v : 0.f; s = fmaf(v, wv8[3], s);
        v = b2f(u1.x) + ha8[4]; v = v > 0.f ? v : 0.f; s = fmaf(v, wv8[4], s);
        v = b2f(u1.y) + ha8[5]; v = v > 0.f ? v : 0.f; s = fmaf(v, wv8[5], s);
        v = b2f(u1.z) + ha8[6]; v = v > 0.f ? v : 0.f; s = fmaf(v, wv8[6], s);
        v = b2f(u1.w) + ha8[7]; v = v > 0.f ? v : 0.f; s = fmaf(v, wv8[7], s);
#pragma unroll
        for (int off = 32; off > 0; off >>= 1) s += __shfl_down(s, off, 64);
        if (l == 0) eS[p] = s;
    }
    __syncthreads();
    float ev = eS[tid];
    red[tid] = ev;
    __syncthreads();
    for (int s = 128; s > 0; s >>= 1) {
        if (tid < s) red[tid] = fmaxf(red[tid], red[tid + s]);
        __syncthreads();
    }
    float mx = red[0];
    __syncthreads();
    float ex = expf(ev - mx);
    red[tid] = ex;
    __syncthreads();
    for (int s = 128; s > 0; s >>= 1) {
        if (tid < s) red[tid] += red[tid + s];
        __syncthreads();
    }
    float inv = 1.0f / red[0];
    float a = ex * inv;
    __syncthreads();
    eS[tid] = a;                     // alpha now in LDS
    if (half == 0 && tid < P_) {
        float m = (t < clen[b] - 1) ? 1.0f : 0.0f;
        alphas_out[((size_t)b * T_ + t) * P_ + tid] = a * m;
    }
    __syncthreads();

    // context: 128 col-threads x 8 cols, two 98-long p-ranges
    int tl = tid & 127;
    int pr = tid >> 7;                       // 0 or 1
    int pp0 = pr * 98;
    int f0 = (half << 10) + tl * 8;
    float s[8] = {};
    if (BF) {
        const ushort* ep = (const ushort*)encv + (size_t)b * P_ * F_ +
                           (size_t)pp0 * F_ + f0;
        for (int p = 0; p < 98; p++) {
            u16x8 u = *(const u16x8*)(ep + (size_t)p * F_);
            float al = eS[pp0 + p];
#pragma unroll
            for (int i = 0; i < 8; i++) s[i] = fmaf(al, b2f(u[i]), s[i]);
        }
    } else {
        const float* ep = (const float*)encv + (size_t)b * P_ * F_ +
                          (size_t)pp0 * F_ + f0;
        for (int p = 0; p < 98; p++) {
            float4 u0 = *(const float4*)(ep + (size_t)p * F_);
            float4 u1 = *(const float4*)(ep + (size_t)p * F_ + 4);
            float al = eS[pp0 + p];
            s[0] = fmaf(al, u0.x, s[0]); s[1] = fmaf(al, u0.y, s[1]);
            s[2] = fmaf(al, u0.z, s[2]); s[3] = fmaf(al, u0.w, s[3]);
            s[4] = fmaf(al, u1.x, s[4]); s[5] = fmaf(al, u1.y, s[5]);
            s[6] = fmaf(al, u1.z, s[6]); s[7] = fmaf(al, u1.w, s[7]);
        }
    }
    if (pr) {
#pragma unroll
        for (int i = 0; i < 8; i++) pc[tl * 8 + i] = s[i];
    }
    __syncthreads();
    if (!pr) {
        const float* gp = combo + (size_t)b * 2560 + 512 + f0;
        float4 ga = *(const float4*)gp;
        float4 gb = *(const float4*)(gp + 4);
        float gv[8] = {ga.x, ga.y, ga.z, ga.w, gb.x, gb.y, gb.z, gb.w};
        ushort o[8];
#pragma unroll
        for (int i = 0; i < 8; i++)
            o[i] = f2b(sigf(gv[i]) * (s[i] + pc[tl * 8 + i]));
        *(u16x8*)(gctxb + (size_t)b * F_ + f0) = *(u16x8*)o;
    }
}

// ---- LSTM pointwise over gate-interleaved z-partials ----
__global__ __launch_bounds__(256)
void lstm_perm(const float* __restrict__ gatesP,   // 4 x B x 2048 (permuted)
               const float* __restrict__ embprojP, // B*T x 2048 (permuted)
               const float* __restrict__ bg,       // 2048 (permuted bih+bhh)
               float* __restrict__ cbuf, ushort* __restrict__ hout, int t) {
    int idx = blockIdx.x * 256 + threadIdx.x;   // B*H
    int b = idx >> 9, j = idx & (H_ - 1);
    int n0 = j * 4;
    float4 g = *(const float4*)(embprojP + ((size_t)b * T_ + t) * 2048 + n0);
    float4 bgv = *(const float4*)(bg + n0);
    g.x += bgv.x; g.y += bgv.y; g.z += bgv.z; g.w += bgv.w;
#pragma unroll
    for (int z = 0; z < 4; z++) {
        float4 p = *(const float4*)(gatesP + ((size_t)z * B_ + b) * 2048 + n0);
        g.x += p.x; g.y += p.y; g.z += p.z; g.w += p.w;
    }
    float cn = sigf(g.y) * cbuf[idx] + sigf(g.x) * tanhf(g.z);
    float hn = sigf(g.w) * tanhf(cn);
    cbuf[idx] = cn;
    hout[idx] = f2b(hn);
}

extern "C" void kernel_launch(void* const* d_in, const int* in_sizes, int n_in,
                              void* d_out, int out_size, void* d_ws, size_t ws_size,
                              hipStream_t stream) {
    const float* enc = (const float*)d_in[0];
    const float* emb = (const float*)d_in[1];
    const float* Wfa = (const float*)d_in[2];
    const float* bfa = (const float*)d_in[3];
    const float* Wha = (const float*)d_in[4];
    const float* bha = (const float*)d_in[5];
    const float* Wv  = (const float*)d_in[6];
    const float* Wh0 = (const float*)d_in[8];
    const float* bh0 = (const float*)d_in[9];
    const float* Wc0 = (const float*)d_in[10];
    const float* bc0 = (const float*)d_in[11];
    const float* gh  = (const float*)d_in[12];
    const float* bth = (const float*)d_in[13];
    const float* gc  = (const float*)d_in[14];
    const float* btc = (const float*)d_in[15];
    const float* Wfb = (const float*)d_in[16];
    const float* bfb = (const float*)d_in[17];
    const float* Wih = (const float*)d_in[18];
    const float* Whh = (const float*)d_in[19];
    const float* bih = (const float*)d_in[20];
    const float* bhh = (const float*)d_in[21];
    const float* Wfc = (const float*)d_in[22];
    const float* bfc = (const float*)d_in[23];
    const int* gt   = (const int*)d_in[24];
    const int* clen = (const int*)d_in[25];

    float* out_pred  = (float*)d_out;                       // (B,T,V)
    float* out_alpha = out_pred + (size_t)B_ * T_ * V_;     // (B,T,P)

    char* wp = (char*)d_ws;
    auto alloc = [&](size_t bytes) {
        char* p = wp;
        wp += (bytes + 255) & ~(size_t)255;
        return p;
    };
    float*  feat     = (float*)alloc((size_t)B_ * F_ * 4);
    float*  cbuf     = (float*)alloc((size_t)B_ * H_ * 4);
    float*  combo    = (float*)alloc((size_t)B_ * 2560 * 4);
    float*  embprojP = (float*)alloc((size_t)B_ * T_ * 2048 * 4);
    float*  gatesP   = (float*)alloc((size_t)4 * B_ * 2048 * 4);
    float*  hcpart   = (float*)alloc((size_t)4 * B_ * 1024 * 4);
    float*  bcp      = (float*)alloc((size_t)NCP_ * 4);
    float*  bg       = (float*)alloc(2048 * 4);
    float*  b0comb   = (float*)alloc(1024 * 4);
    float*  g0comb   = (float*)alloc(1024 * 4);
    float*  bt0comb  = (float*)alloc(1024 * 4);
    ushort* hb0      = (ushort*)alloc((size_t)B_ * H_ * 2);
    ushort* hb1      = (ushort*)alloc((size_t)B_ * H_ * 2);
    ushort* gctxb    = (ushort*)alloc((size_t)B_ * F_ * 2);
    ushort* embxb    = (ushort*)alloc((size_t)B_ * T_ * E_ * 2);
    ushort* fattb    = (ushort*)alloc((size_t)B_ * P_ * NF_ * 2);
    ushort* featb    = (ushort*)alloc((size_t)B_ * F_ * 2);
    ushort* Wfab     = (ushort*)alloc((size_t)NF_ * F_ * 2);
    ushort* WihEbP   = (ushort*)alloc((size_t)2048 * E_ * 2);
    ushort* WihFbP   = (ushort*)alloc((size_t)2048 * F_ * 2);
    ushort* WhhbP    = (ushort*)alloc((size_t)2048 * H_ * 2);
    ushort* Wcp      = (ushort*)alloc((size_t)NCP_ * H_ * 2);
    ushort* W0comb   = (ushort*)alloc((size_t)1024 * F_ * 2);
    ushort* encb     = (ushort*)alloc((size_t)B_ * P_ * F_ * 2);
    const bool big = ((size_t)(wp - (char*)d_ws) <= ws_size);

    auto castM = [&](const float* s, ushort* d, long long rows, int cols, int sld, int srows) {
        long long total = rows * (long long)cols;
        cast_mat<<<(int)((total + 1023) / 1024), 256, 0, stream>>>(s, d, total, cols, sld, srows);
    };

    // ---- one-time casts / permutes / bias builds ----
    castM(Wfa, Wfab, NF_, F_, F_, NF_);
    cast_perm<<<(2048 * E_) / 1024, 256, 0, stream>>>(Wih, WihEbP, E_, E_ + F_);
    cast_perm<<<(2048 * F_) / 1024, 256, 0, stream>>>(Wih + E_, WihFbP, F_, E_ + F_);
    cast_perm<<<(2048 * H_) / 1024, 256, 0, stream>>>(Whh, WhhbP, H_, H_);
    castM(Wha, Wcp, NF_, H_, H_, NF_);
    castM(Wfb, Wcp + (size_t)512 * H_, F_, H_, H_, F_);
    castM(Wfc, Wcp + (size_t)2560 * H_, NPAD_, H_, H_, V_);
    castM(Wh0, W0comb, H_, F_, F_, H_);
    castM(Wc0, W0comb + (size_t)H_ * F_, H_, F_, F_, H_);
    build_bg<<<2048 / 256, 256, 0, stream>>>(bih, bhh, bg);
    build_bcp<<<(NCP_ + 255) / 256, 256, 0, stream>>>(bha, bfb, bfc, bcp);
    hipMemcpyAsync(b0comb, bh0, H_ * 4, hipMemcpyDeviceToDevice, stream);
    hipMemcpyAsync(b0comb + H_, bc0, H_ * 4, hipMemcpyDeviceToDevice, stream);
    hipMemcpyAsync(g0comb, gh, H_ * 4, hipMemcpyDeviceToDevice, stream);
    hipMemcpyAsync(g0comb + H_, gc, H_ * 4, hipMemcpyDeviceToDevice, stream);
    hipMemcpyAsync(bt0comb, bth, H_ * 4, hipMemcpyDeviceToDevice, stream);
    hipMemcpyAsync(bt0comb + H_, btc, H_ * 4, hipMemcpyDeviceToDevice, stream);

    // ---- init state: fused mean+cast ----
    if (big) mean_cast_kernel<<<B_ * 8, 256, 0, stream>>>(enc, encb, feat);
    else     mean_kernel<<<B_ * 8, 256, 0, stream>>>(enc, feat);
    castM(feat, featb, B_, F_, F_, B_);
    mfma_gemm<32, MEPI_NONE, 0><<<dim3(1024 / 128, B_ / 32, 4), 256, 0, stream>>>(
        featb, F_, W0comb, F_, F_, nullptr, 0, nullptr, 0, 0,
        nullptr, hcpart, 1024, nullptr, B_, 1024, nullptr, 0);
    h0c0_final<<<(B_ * H_) / 256, 256, 0, stream>>>(hcpart, b0comb, g0comb, bt0comb, cbuf, hb0);
    gather_b<<<(B_ * T_ * E_) / 1024, 256, 0, stream>>>(emb, gt, embxb);

    // ---- feat_att (bf16 out) ----
    if (big) {
        mfma_gemm<128, MEPI_BIASB, 0><<<dim3(NF_ / 128, (B_ * P_) / 128, 1), 256, 0, stream>>>(
            encb, F_, Wfab, F_, F_, nullptr, 0, nullptr, 0, 0,
            bfa, fattb, NF_, nullptr, B_ * P_, NF_, nullptr, 0);
    } else {
        gemm_biasb<<<dim3(NF_ / 64, (B_ * P_) / 64), 256, 0, stream>>>(
            enc, F_, Wfa, F_, bfa, fattb, NF_, B_ * P_, NF_, F_);
    }
    // ---- embprojP = embx @ WihEbP^T (fp32, gate-interleaved cols) ----
    mfma_gemm<128, MEPI_NONE, 0><<<dim3(2048 / 128, (B_ * T_) / 128, 1), 256, 0, stream>>>(
        embxb, E_, WihEbP, E_, E_, nullptr, 0, nullptr, 0, 0,
        nullptr, embprojP, 2048, nullptr, B_ * T_, 2048, nullptr, 0);

    // ---- combo(0) from h0 ----
    mfma_gemm<32, MEPI_BIAS, 0><<<dim3(2560 / 128, B_ / 32, 1), 256, 0, stream>>>(
        hb0, H_, Wcp, H_, H_, nullptr, 0, nullptr, 0, 0,
        bcp, combo, 2560, nullptr, B_, 2560, nullptr, 0);

    // ---- recurrent scan: 4 launches per step ----
    for (int t = 0; t < T_; t++) {
        ushort* hin  = (t & 1) ? hb1 : hb0;
        ushort* hout = (t & 1) ? hb0 : hb1;
        if (big) attn_ctx<1><<<B_ * 2, 256, 0, stream>>>(encb, fattb, combo, Wv,
                                                         out_alpha, clen, gctxb, t);
        else     attn_ctx<0><<<B_ * 2, 256, 0, stream>>>(enc, fattb, combo, Wv,
                                                         out_alpha, clen, gctxb, t);
        // gates partials: z=4, 256 blocks
        mfma_gemm<32, MEPI_NONE, 1><<<dim3(2048 / 128, B_ / 32, 4), 256, 0, stream>>>(
            gctxb, F_, WihFbP, F_, F_, hin, H_, WhhbP, H_, H_,
            nullptr, gatesP, 2048, nullptr, B_, 2048, nullptr, 0);
        lstm_perm<<<(B_ * H_) / 256, 256, 0, stream>>>(
            gatesP, embprojP, bg, cbuf, hout, t);
        // combo(t+1) + preds(t) from h_new
        mfma_gemm<32, MEPI_COMBOPRED, 0><<<dim3(NCP_ / 128, B_ / 32, 1), 256, 0, stream>>>(
            hout, H_, Wcp, H_, H_, nullptr, 0, nullptr, 0, 0,
            bcp, combo, 2560, out_pred + (size_t)t * V_, B_, NCP_, clen, t);
    }
}